// Round 4
// baseline (93.020 us; speedup 1.0000x reference)
//
#include <hip/hip_runtime.h>
#include <hip/hip_bf16.h>

#define TT   1024
#define NF   32
#define NB   128
#define HID  16
#define KK   5
#define DD   4
#define FPAD 24
#define XROW (FPAD + TT + FPAD)   // 1072 bf16 per (f,b) row

typedef short short8   __attribute__((ext_vector_type(8)));
typedef short short8_u __attribute__((ext_vector_type(8), aligned(4)));
typedef float floatx4  __attribute__((ext_vector_type(4)));

__device__ inline ushort f2bf(float f) {
    union { float f; uint u; } v; v.f = f;
    uint r = v.u + 0x7fffu + ((v.u >> 16) & 1u);
    return (ushort)(r >> 16);
}
__device__ inline float bf2f(ushort h) {
    union { uint u; float f; } v; v.u = ((uint)h) << 16; return v.f;
}
__device__ inline uint pack_bf2(float a, float b) {
    return (uint)f2bf(a) | ((uint)f2bf(b) << 16);
}

// ---------------- pre-kernel: x (B,T,F) f32 -> xhi/xlo (F,B,XROW) bf16 ----------------
__global__ __launch_bounds__(256) void transpose_k(
    const float* __restrict__ x, ushort* __restrict__ xhi, ushort* __restrict__ xlo)
{
    const int tc = blockIdx.x;   // T chunk (0..3), 256 t's each
    const int b  = blockIdx.y;
    const int tid = threadIdx.x;

    __shared__ float ls[256 * 40];   // [t_local][f], stride 40 floats

    const float4* xb = (const float4*)(x + ((size_t)b * TT + tc * 256) * NF);
    #pragma unroll
    for (int i = 0; i < 8; ++i) {
        int v = tid + 256 * i;                 // float4 index within chunk
        float4 val = xb[v];
        int tl = v >> 3, f0 = 4 * (v & 7);
        *(float4*)&ls[tl * 40 + f0] = val;     // 16B-aligned (40*4 and f0*4 mult of 16)
    }
    __syncthreads();

    const int f = tid & 31, tb = tid >> 5;
    ushort hb[32] __attribute__((aligned(16)));
    ushort lb[32] __attribute__((aligned(16)));
    #pragma unroll
    for (int m = 0; m < 32; ++m) {
        float v = ls[(tb * 32 + m) * 40 + f];
        ushort h = f2bf(v);
        float hf = bf2f(h);
        hb[m] = h;
        lb[m] = f2bf(v - hf);
    }
    size_t di = (size_t)(f * NB + b) * XROW + FPAD + tc * 256 + tb * 32;
    uint4* dh = (uint4*)(xhi + di); const uint4* sh = (const uint4*)hb;
    uint4* dl = (uint4*)(xlo + di); const uint4* sl = (const uint4*)lb;
    #pragma unroll
    for (int q = 0; q < 4; ++q) { dh[q] = sh[q]; dl[q] = sl[q]; }

    // zero the pads (front by tc==0 blocks, back by tc==3 blocks)
    if (tc == 0) {
        for (int i = tid; i < NF * FPAD; i += 256) {
            int fz = i / FPAD, e = i % FPAD;
            size_t r = (size_t)(fz * NB + b) * XROW + e;
            xhi[r] = 0; xlo[r] = 0;
        }
    } else if (tc == 3) {
        for (int i = tid; i < NF * FPAD; i += 256) {
            int fz = i / FPAD, e = i % FPAD;
            size_t r = (size_t)(fz * NB + b) * XROW + FPAD + TT + e;
            xhi[r] = 0; xlo[r] = 0;
        }
    }
}

// ---------------- fused branch kernel: all-MFMA conv1+conv2 ----------------
// Block = (b,f); 4 waves, wave = pool segment (256 cols). Per-wave private
// swizzled LDS tile of h1 (288 rows x 16 cin, bf16).
// Tile addressing: 64B line = 2 rows; 16B chunk index within line =
// ((r&1)*2 + cin/8) ^ ((r>>1)&3)  -> 2-way bank aliasing only.
__global__ __launch_bounds__(256, 4) void fused_kernel(
    const ushort* __restrict__ xhi, const ushort* __restrict__ xlo,
    const float* __restrict__ w1, const float* __restrict__ b1,
    const float* __restrict__ w2, const float* __restrict__ b2,
    const float* __restrict__ pw, const float* __restrict__ pb,
    float* __restrict__ out)
{
    const int f = blockIdx.x & 31;
    const int b = blockIdx.x >> 5;
    const int tid  = threadIdx.x;
    const int wave = tid >> 6;
    const int lane = tid & 63;
    const int g    = lane >> 4;
    const int crow = lane & 15;
    const bool odd = (crow & 1) != 0;

    __shared__ ushort tiles[4][4608];       // 144 lines * 32 ushorts per wave
    __shared__ float  pool_lds[HID * DD];
    ushort* tile = tiles[wave];

    // ---- conv1 A-frags: A0 = taps 0..4 at j=0..4 ; A1 = taps 0..4 at j=1..5 ----
    short8 a0 = {0,0,0,0,0,0,0,0}, a1 = {0,0,0,0,0,0,0,0};
    if (g == 0) {
        const float* w1f = w1 + (size_t)f * HID * KK + crow * KK;
        #pragma unroll
        for (int j = 0; j < 8; ++j) {
            if (j < 5)           a0[j] = (short)f2bf(w1f[j]);
            if (j >= 1 && j < 6) a1[j] = (short)f2bf(w1f[j - 1]);
        }
    }
    float bias1[4], bias2[4];
    #pragma unroll
    for (int rr = 0; rr < 4; ++rr) {
        bias1[rr] = b1[f * HID + 4 * g + rr];
        bias2[rr] = b2[f * HID + 4 * g + rr];
    }

    // ---- conv2 A-frags (as round 2): kk = 8g+j -> cin = 8*(g&1)+j, dk = g>>1 ----
    const int cin0 = (g & 1) * 8;
    const int dk   = g >> 1;
    short8 af[3];
    {
        const float* w2f = w2 + (size_t)f * HID * HID * KK;
        #pragma unroll
        for (int p = 0; p < 3; ++p) {
            int k = 2 * p + dk;
            #pragma unroll
            for (int j = 0; j < 8; ++j) {
                float wv = (k < KK) ? w2f[crow * (HID * KK) + (cin0 + j) * KK + k] : 0.f;
                af[p][j] = (short)f2bf(wv);
            }
        }
    }

    const int t0seg = wave * 256;
    // xh[i] = xhi row base; actual x[t] lives at index FPAD + t  (pads zeroed)
    const ushort* xh = xhi + (size_t)(f * NB + b) * XROW;
    const ushort* xl = xlo + (size_t)(f * NB + b) * XROW;

    // ---- conv1: 18 subtiles of 16 t's -> tile rows [0,288) (t = t0seg-16+r) ----
    #pragma unroll
    for (int us = 0; us < 18; ++us) {
        const int tbase = t0seg - 16 + 16 * us;
        const int r1 = 16 * us + crow;
        const int woff = (r1 >> 1) * 32
                       + (((((r1 & 1) << 1) | (g >> 1)) ^ ((r1 >> 1) & 3)) << 3)
                       + ((g & 1) << 2);
        uint2 wv;
        if (tbase < 0 || tbase >= TT) {        // wave-uniform: fully out of range
            wv = make_uint2(0u, 0u);
        } else {
            // even base: element index FPAD + tbase + (crow&~1) - 2 ; 4B-aligned
            const int s0e = tbase + (crow & ~1) + (FPAD - 2);
            short8 bh = *(const short8_u*)(xh + s0e);
            short8 bl = *(const short8_u*)(xl + s0e);
            floatx4 ae = {bias1[0], bias1[1], bias1[2], bias1[3]};
            floatx4 ao = ae;
            ae = __builtin_amdgcn_mfma_f32_16x16x32_bf16(a0, bh, ae, 0, 0, 0);
            ae = __builtin_amdgcn_mfma_f32_16x16x32_bf16(a0, bl, ae, 0, 0, 0);
            ao = __builtin_amdgcn_mfma_f32_16x16x32_bf16(a1, bh, ao, 0, 0, 0);
            ao = __builtin_amdgcn_mfma_f32_16x16x32_bf16(a1, bl, ao, 0, 0, 0);
            float h0 = fmaxf(odd ? ao[0] : ae[0], 0.f);
            float h1v = fmaxf(odd ? ao[1] : ae[1], 0.f);
            float h2 = fmaxf(odd ? ao[2] : ae[2], 0.f);
            float h3 = fmaxf(odd ? ao[3] : ae[3], 0.f);
            wv = make_uint2(pack_bf2(h0, h1v), pack_bf2(h2, h3));
        }
        *(uint2*)&tile[woff] = wv;
    }

    // ---- conv2 + relu + pool (B-frags from swizzled tile) ----
    float psum[4] = {0.f, 0.f, 0.f, 0.f};
    #pragma unroll
    for (int ti = 0; ti < 4; ++ti) {
        #pragma unroll
        for (int st = 0; st < 4; ++st) {
            floatx4 acc = {bias2[0], bias2[1], bias2[2], bias2[3]};
            #pragma unroll
            for (int p = 0; p < 3; ++p) {
                const int r = ti * 64 + st * 16 + crow + 2 * p + dk + 14;
                const int roff = (r >> 1) * 32
                               + (((((r & 1) << 1) | (g & 1)) ^ ((r >> 1) & 3)) << 3);
                const short8 bfr = *(const short8*)&tile[roff];
                acc = __builtin_amdgcn_mfma_f32_16x16x32_bf16(af[p], bfr, acc, 0, 0, 0);
            }
            #pragma unroll
            for (int rr = 0; rr < 4; ++rr) psum[rr] += fmaxf(acc[rr], 0.f);
        }
    }

    // ---- pool reduce across the 16 col-lanes of each group ----
    #pragma unroll
    for (int rr = 0; rr < 4; ++rr) {
        float v = psum[rr];
        v += __shfl_xor(v, 1, 64);
        v += __shfl_xor(v, 2, 64);
        v += __shfl_xor(v, 4, 64);
        v += __shfl_xor(v, 8, 64);
        if (crow == 0) pool_lds[(4 * g + rr) * DD + wave] = v * (1.f / 256.f);
    }
    __syncthreads();

    // ---- final GEMV ----
    if (tid < DD) {
        const float* pwr = pw + ((size_t)f * DD + tid) * (HID * DD);
        float o = pb[f * DD + tid];
        #pragma unroll
        for (int i = 0; i < HID * DD; ++i) o = fmaf(pwr[i], pool_lds[i], o);
        out[((size_t)b * NF + f) * DD + tid] = o;
    }
}

extern "C" void kernel_launch(void* const* d_in, const int* in_sizes, int n_in,
                              void* d_out, int out_size, void* d_ws, size_t ws_size,
                              hipStream_t stream) {
    const float* x  = (const float*)d_in[0];
    // d_in[1] = lengths (unused by reference)
    const float* w1 = (const float*)d_in[2];
    const float* b1 = (const float*)d_in[3];
    const float* w2 = (const float*)d_in[4];
    const float* b2 = (const float*)d_in[5];
    const float* pw = (const float*)d_in[6];
    const float* pb = (const float*)d_in[7];
    float* out = (float*)d_out;

    ushort* xhi = (ushort*)d_ws;
    ushort* xlo = xhi + (size_t)NF * NB * XROW;

    transpose_k<<<dim3(4, NB), dim3(256), 0, stream>>>(x, xhi, xlo);
    fused_kernel<<<dim3(NF * NB), dim3(256), 0, stream>>>(xhi, xlo, w1, b1, w2, b2, pw, pb, out);
}

// Round 5
// 46.436 us; speedup vs baseline: 2.0032x; 2.0032x over previous
//
#include <hip/hip_runtime.h>
#include <hip/hip_bf16.h>

#define TT   1024
#define NF   32
#define NB   128
#define HID  16
#define KK   5
#define DD   4
#define FPAD 24
#define XROW (FPAD + TT + FPAD)          // 1072 bf16 per (f,b) row
#define WPO  ((size_t)NF * NB * XROW)    // ushort offset of weight pack in ws

typedef short short8   __attribute__((ext_vector_type(8)));
typedef short short8_u __attribute__((ext_vector_type(8), aligned(4)));
typedef float floatx4  __attribute__((ext_vector_type(4)));

__device__ inline ushort f2bf(float f) {
    union { float f; uint u; } v; v.f = f;
    uint r = v.u + 0x7fffu + ((v.u >> 16) & 1u);
    return (ushort)(r >> 16);
}
__device__ inline uint pack_bf2(float a, float b) {
    return (uint)f2bf(a) | ((uint)f2bf(b) << 16);
}

// ---- pre-kernel: transpose x to (F,B,XROW) bf16 + weight fragment pack ----
// grid (5, NB): blockIdx.x<4 = transpose chunks; blockIdx.x==4 & b<NF = weights.
__global__ __launch_bounds__(256) void prep_k(
    const float* __restrict__ x, const float* __restrict__ w1,
    const float* __restrict__ w2, ushort* __restrict__ xhi,
    ushort* __restrict__ wpack)
{
    const int tc  = blockIdx.x;
    const int b   = blockIdx.y;
    const int tid = threadIdx.x;

    if (tc == 4) {
        // ---- weight prep: one block per field (b<NF), thread=lane (tid<64) ----
        if (b >= NF || tid >= 64) return;
        const int f = b, lane = tid;
        const int g = lane >> 4, crow = lane & 15;
        short8 a0 = {0,0,0,0,0,0,0,0}, a1 = a0, af[3] = {a0, a0, a0};
        if (g == 0) {
            const float* w1f = w1 + (size_t)f * HID * KK + crow * KK;
            #pragma unroll
            for (int j = 0; j < 8; ++j) {
                if (j < 5)           a0[j] = (short)f2bf(w1f[j]);
                if (j >= 1 && j < 6) a1[j] = (short)f2bf(w1f[j - 1]);
            }
        }
        const int cin0 = (g & 1) * 8, dk = g >> 1;
        const float* w2f = w2 + (size_t)f * HID * HID * KK;
        #pragma unroll
        for (int p = 0; p < 3; ++p) {
            int k = 2 * p + dk;
            #pragma unroll
            for (int j = 0; j < 8; ++j)
                af[p][j] = (k < KK) ? (short)f2bf(w2f[crow * (HID * KK) + (cin0 + j) * KK + k]) : (short)0;
        }
        short8* dst = (short8*)wpack + ((size_t)f * 64 + lane) * 5;
        dst[0] = a0; dst[1] = a1; dst[2] = af[0]; dst[3] = af[1]; dst[4] = af[2];
        return;
    }

    __shared__ float ls[256 * 40];   // [t_local][f], stride 40 floats

    const float4* xb = (const float4*)(x + ((size_t)b * TT + tc * 256) * NF);
    #pragma unroll
    for (int i = 0; i < 8; ++i) {
        int v = tid + 256 * i;
        float4 val = xb[v];
        int tl = v >> 3, f0 = 4 * (v & 7);
        *(float4*)&ls[tl * 40 + f0] = val;
    }
    __syncthreads();

    const int f = tid & 31, tb = tid >> 5;
    ushort hb[32] __attribute__((aligned(16)));
    #pragma unroll
    for (int m = 0; m < 32; ++m)
        hb[m] = f2bf(ls[(tb * 32 + m) * 40 + f]);
    size_t di = (size_t)(f * NB + b) * XROW + FPAD + tc * 256 + tb * 32;
    uint4* dh = (uint4*)(xhi + di); const uint4* sh = (const uint4*)hb;
    #pragma unroll
    for (int q = 0; q < 4; ++q) dh[q] = sh[q];

    if (tc == 0) {
        for (int i = tid; i < NF * FPAD; i += 256) {
            int fz = i / FPAD, e = i % FPAD;
            xhi[(size_t)(fz * NB + b) * XROW + e] = 0;
        }
    } else if (tc == 3) {
        for (int i = tid; i < NF * FPAD; i += 256) {
            int fz = i / FPAD, e = i % FPAD;
            xhi[(size_t)(fz * NB + b) * XROW + FPAD + TT + e] = 0;
        }
    }
}

// ---- fused branch kernel: all-MFMA conv1+conv2 on packed weights ----
__global__ __launch_bounds__(256, 4) void fused_kernel(
    const ushort* __restrict__ xhi, const ushort* __restrict__ wpack,
    const float* __restrict__ b1, const float* __restrict__ b2,
    const float* __restrict__ pw, const float* __restrict__ pb,
    float* __restrict__ out)
{
    const int f = blockIdx.x & 31;
    const int b = blockIdx.x >> 5;
    const int tid  = threadIdx.x;
    const int wave = tid >> 6;
    const int lane = tid & 63;
    const int g    = lane >> 4;
    const int crow = lane & 15;
    const bool odd = (crow & 1) != 0;

    __shared__ ushort tiles[4][4608];       // 144 lines * 32 ushorts per wave
    __shared__ float  pool_lds[HID * DD];
    ushort* tile = tiles[wave];

    // ---- packed weights: 5 coalesced 16B loads ----
    const short8* wl = (const short8*)wpack + ((size_t)f * 64 + lane) * 5;
    const short8 a0 = wl[0], a1 = wl[1];
    const short8 af0 = wl[2], af1 = wl[3], af2 = wl[4];
    const float4 b1v = *(const float4*)(b1 + f * HID + 4 * g);
    const float4 b2v = *(const float4*)(b2 + f * HID + 4 * g);
    const int dk = g >> 1;

    const int t0seg = wave * 256;
    const ushort* xh = xhi + (size_t)(f * NB + b) * XROW;

    // ---- prefetch all 18 conv1 B-fragments (even-base parity trick) ----
    short8 bh[18];
    #pragma unroll
    for (int us = 0; us < 18; ++us) {
        const int s0e = (t0seg - 16 + 16 * us) + (crow & ~1) + (FPAD - 2);
        bh[us] = *(const short8_u*)(xh + s0e);
    }

    // ---- conv1: 18 subtiles -> swizzled LDS tile rows [0,288) ----
    #pragma unroll
    for (int us = 0; us < 18; ++us) {
        const int tbase = t0seg - 16 + 16 * us;
        const int r1 = 16 * us + crow;
        const int woff = (r1 >> 1) * 32
                       + (((((r1 & 1) << 1) | (g >> 1)) ^ ((r1 >> 1) & 3)) << 3)
                       + ((g & 1) << 2);
        uint2 wv;
        if (tbase < 0 || tbase >= TT) {        // wave-uniform: rows are h1 zero-halo
            wv = make_uint2(0u, 0u);
        } else {
            floatx4 ae = {b1v.x, b1v.y, b1v.z, b1v.w};
            floatx4 ao = ae;
            ae = __builtin_amdgcn_mfma_f32_16x16x32_bf16(a0, bh[us], ae, 0, 0, 0);
            ao = __builtin_amdgcn_mfma_f32_16x16x32_bf16(a1, bh[us], ao, 0, 0, 0);
            float h0  = fmaxf(odd ? ao[0] : ae[0], 0.f);
            float h1v = fmaxf(odd ? ao[1] : ae[1], 0.f);
            float h2  = fmaxf(odd ? ao[2] : ae[2], 0.f);
            float h3  = fmaxf(odd ? ao[3] : ae[3], 0.f);
            wv = make_uint2(pack_bf2(h0, h1v), pack_bf2(h2, h3));
        }
        *(uint2*)&tile[woff] = wv;
    }

    // ---- conv2 + relu + pool (B-frags from swizzled tile) ----
    float psum[4] = {0.f, 0.f, 0.f, 0.f};
    #pragma unroll
    for (int ti = 0; ti < 4; ++ti) {
        #pragma unroll
        for (int st = 0; st < 4; ++st) {
            floatx4 acc = {b2v.x, b2v.y, b2v.z, b2v.w};
            #pragma unroll
            for (int p = 0; p < 3; ++p) {
                const int r = ti * 64 + st * 16 + crow + 2 * p + dk + 14;
                const int roff = (r >> 1) * 32
                               + (((((r & 1) << 1) | (g & 1)) ^ ((r >> 1) & 3)) << 3);
                const short8 bfr = *(const short8*)&tile[roff];
                const short8 afp = (p == 0) ? af0 : ((p == 1) ? af1 : af2);
                acc = __builtin_amdgcn_mfma_f32_16x16x32_bf16(afp, bfr, acc, 0, 0, 0);
            }
            #pragma unroll
            for (int rr = 0; rr < 4; ++rr) psum[rr] += fmaxf(acc[rr], 0.f);
        }
    }

    // ---- pool reduce across the 16 col-lanes of each group ----
    #pragma unroll
    for (int rr = 0; rr < 4; ++rr) {
        float v = psum[rr];
        v += __shfl_xor(v, 1, 64);
        v += __shfl_xor(v, 2, 64);
        v += __shfl_xor(v, 4, 64);
        v += __shfl_xor(v, 8, 64);
        if (crow == 0) pool_lds[(4 * g + rr) * DD + wave] = v * (1.f / 256.f);
    }
    __syncthreads();

    // ---- final GEMV ----
    if (tid < DD) {
        const float* pwr = pw + ((size_t)f * DD + tid) * (HID * DD);
        float o = pb[f * DD + tid];
        #pragma unroll
        for (int i = 0; i < HID * DD; ++i) o = fmaf(pwr[i], pool_lds[i], o);
        out[((size_t)b * NF + f) * DD + tid] = o;
    }
}

extern "C" void kernel_launch(void* const* d_in, const int* in_sizes, int n_in,
                              void* d_out, int out_size, void* d_ws, size_t ws_size,
                              hipStream_t stream) {
    const float* x  = (const float*)d_in[0];
    // d_in[1] = lengths (unused by reference)
    const float* w1 = (const float*)d_in[2];
    const float* b1 = (const float*)d_in[3];
    const float* w2 = (const float*)d_in[4];
    const float* b2 = (const float*)d_in[5];
    const float* pw = (const float*)d_in[6];
    const float* pb = (const float*)d_in[7];
    float* out = (float*)d_out;

    ushort* xhi   = (ushort*)d_ws;
    ushort* wpack = xhi + WPO;

    prep_k<<<dim3(5, NB), dim3(256), 0, stream>>>(x, w1, w2, xhi, wpack);
    fused_kernel<<<dim3(NF * NB), dim3(256), 0, stream>>>(xhi, wpack, b1, b2, pw, pb, out);
}

// Round 6
// 40.294 us; speedup vs baseline: 2.3085x; 1.1524x over previous
//
#include <hip/hip_runtime.h>
#include <hip/hip_bf16.h>

#define TT   1024
#define NF   32
#define NB   128
#define HID  16
#define KK   5
#define DD   4
#define FPAD 24
#define XROW (FPAD + TT + FPAD)          // 1072 bf16 per (f,b) row
#define WPO  ((size_t)NF * NB * XROW)    // ushort offset of weight pack in ws

typedef short short8   __attribute__((ext_vector_type(8)));
typedef short short8_u __attribute__((ext_vector_type(8), aligned(4)));
typedef float floatx4  __attribute__((ext_vector_type(4)));

__device__ inline ushort f2bf(float f) {
    union { float f; uint u; } v; v.f = f;
    uint r = v.u + 0x7fffu + ((v.u >> 16) & 1u);
    return (ushort)(r >> 16);
}
__device__ inline uint cvt_pk_bf16(float lo, float hi) {
    uint r;
    asm("v_cvt_pk_bf16_f32 %0, %1, %2" : "=v"(r) : "v"(lo), "v"(hi));
    return r;
}

// ---- pre-kernel: transpose x to (F,B,XROW) bf16 + weight fragment pack ----
__global__ __launch_bounds__(256) void prep_k(
    const float* __restrict__ x, const float* __restrict__ w1,
    const float* __restrict__ w2, ushort* __restrict__ xhi,
    ushort* __restrict__ wpack)
{
    const int tc  = blockIdx.x;
    const int b   = blockIdx.y;
    const int tid = threadIdx.x;

    if (tc == 4) {
        if (b >= NF || tid >= 64) return;
        const int f = b, lane = tid;
        const int g = lane >> 4, crow = lane & 15;
        short8 a0 = {0,0,0,0,0,0,0,0}, a1 = a0, af[3] = {a0, a0, a0};
        if (g == 0) {
            const float* w1f = w1 + (size_t)f * HID * KK + crow * KK;
            #pragma unroll
            for (int j = 0; j < 8; ++j) {
                if (j < 5)           a0[j] = (short)f2bf(w1f[j]);
                if (j >= 1 && j < 6) a1[j] = (short)f2bf(w1f[j - 1]);
            }
        }
        const int cin0 = (g & 1) * 8, dk = g >> 1;
        const float* w2f = w2 + (size_t)f * HID * HID * KK;
        #pragma unroll
        for (int p = 0; p < 3; ++p) {
            int k = 2 * p + dk;
            #pragma unroll
            for (int j = 0; j < 8; ++j)
                af[p][j] = (k < KK) ? (short)f2bf(w2f[crow * (HID * KK) + (cin0 + j) * KK + k]) : (short)0;
        }
        short8* dst = (short8*)wpack + ((size_t)f * 64 + lane) * 5;
        dst[0] = a0; dst[1] = a1; dst[2] = af[0]; dst[3] = af[1]; dst[4] = af[2];
        return;
    }

    __shared__ float ls[256 * 40];

    const float4* xb = (const float4*)(x + ((size_t)b * TT + tc * 256) * NF);
    #pragma unroll
    for (int i = 0; i < 8; ++i) {
        int v = tid + 256 * i;
        float4 val = xb[v];
        int tl = v >> 3, f0 = 4 * (v & 7);
        *(float4*)&ls[tl * 40 + f0] = val;
    }
    __syncthreads();

    const int f = tid & 31, tb = tid >> 5;
    ushort hb[32] __attribute__((aligned(16)));
    #pragma unroll
    for (int m = 0; m < 32; ++m)
        hb[m] = f2bf(ls[(tb * 32 + m) * 40 + f]);
    size_t di = (size_t)(f * NB + b) * XROW + FPAD + tc * 256 + tb * 32;
    uint4* dh = (uint4*)(xhi + di); const uint4* sh = (const uint4*)hb;
    #pragma unroll
    for (int q = 0; q < 4; ++q) dh[q] = sh[q];

    if (tc == 0) {
        for (int i = tid; i < NF * FPAD; i += 256) {
            int fz = i / FPAD, e = i % FPAD;
            xhi[(size_t)(fz * NB + b) * XROW + e] = 0;
        }
    } else if (tc == 3) {
        for (int i = tid; i < NF * FPAD; i += 256) {
            int fz = i / FPAD, e = i % FPAD;
            xhi[(size_t)(fz * NB + b) * XROW + FPAD + TT + e] = 0;
        }
    }
}

// ---- fused branch kernel: all-MFMA conv1+conv2, immediate-offset LDS ----
__global__ __launch_bounds__(256, 4) void fused_kernel(
    const ushort* __restrict__ xhi, const ushort* __restrict__ wpack,
    const float* __restrict__ b1, const float* __restrict__ b2,
    const float* __restrict__ pw, const float* __restrict__ pb,
    float* __restrict__ out)
{
    const int f = blockIdx.x & 31;
    const int b = blockIdx.x >> 5;
    const int tid  = threadIdx.x;
    const int wave = tid >> 6;
    const int lane = tid & 63;
    const int g    = lane >> 4;
    const int crow = lane & 15;
    const bool odd = (crow & 1) != 0;

    __shared__ ushort tiles[4][4608];       // 144 lines * 32 ushorts per wave
    __shared__ float  pool_lds[HID * DD];
    ushort* tile = tiles[wave];

    // ---- packed weights: 5 coalesced 16B loads ----
    const short8* wl = (const short8*)wpack + ((size_t)f * 64 + lane) * 5;
    const short8 a0 = wl[0], a1 = wl[1];
    const short8 af0 = wl[2], af1 = wl[3], af2 = wl[4];
    const float4 b1v = *(const float4*)(b1 + f * HID + 4 * g);
    const float4 b2v = *(const float4*)(b2 + f * HID + 4 * g);
    const int dk = g >> 1;

    const int t0seg = wave * 256;
    const ushort* xh = xhi + (size_t)(f * NB + b) * XROW;

    // ---- lane-constant swizzled LDS bases ----
    // conv1 write: r1 = 16*us + crow -> woff = woffbase + 256*us
    const int woffbase = (crow >> 1) * 32
                       + (((((crow & 1) << 1) | (g >> 1)) ^ ((crow >> 1) & 3)) << 3)
                       + ((g & 1) << 2);
    ushort* wdst = tile + woffbase;
    // conv2 read: r = 2*(ti*32+st*8+p) + E, E = crow + dk + 14
    // roff = roffbase[p] + ti*1024 + st*256
    const int E  = crow + dk + 14;
    const int Ch = ((E & 1) << 1) | (g & 1);
    const ushort* tp0 = tile + ((E >> 1) + 0) * 32 + ((Ch ^ (((E >> 1) + 0) & 3)) << 3);
    const ushort* tp1 = tile + ((E >> 1) + 1) * 32 + ((Ch ^ (((E >> 1) + 1) & 3)) << 3);
    const ushort* tp2 = tile + ((E >> 1) + 2) * 32 + ((Ch ^ (((E >> 1) + 2) & 3)) << 3);

    // ---- prefetch all 18 conv1 B-fragments (1 base + imm offsets) ----
    const ushort* xbase = xh + (t0seg - 16 + (crow & ~1) + (FPAD - 2));
    short8 bh[18];
    #pragma unroll
    for (int us = 0; us < 18; ++us)
        bh[us] = *(const short8_u*)(xbase + 16 * us);

    // ---- conv1: 18 subtiles -> swizzled LDS tile rows [0,288) ----
    #pragma unroll
    for (int us = 0; us < 18; ++us) {
        const int tbase = t0seg - 16 + 16 * us;
        uint2 wv;
        if (tbase < 0 || tbase >= TT) {        // wave-uniform: zero halo rows
            wv = make_uint2(0u, 0u);
        } else {
            floatx4 ae = {b1v.x, b1v.y, b1v.z, b1v.w};
            floatx4 ao = ae;
            ae = __builtin_amdgcn_mfma_f32_16x16x32_bf16(a0, bh[us], ae, 0, 0, 0);
            ao = __builtin_amdgcn_mfma_f32_16x16x32_bf16(a1, bh[us], ao, 0, 0, 0);
            float h0  = fmaxf(odd ? ao[0] : ae[0], 0.f);
            float h1v = fmaxf(odd ? ao[1] : ae[1], 0.f);
            float h2  = fmaxf(odd ? ao[2] : ae[2], 0.f);
            float h3  = fmaxf(odd ? ao[3] : ae[3], 0.f);
            wv = make_uint2(cvt_pk_bf16(h0, h1v), cvt_pk_bf16(h2, h3));
        }
        *(uint2*)(wdst + 256 * us) = wv;
    }

    // ---- conv2 + relu + pool (imm-offset reads from swizzled tile) ----
    float psum[4] = {0.f, 0.f, 0.f, 0.f};
    #pragma unroll
    for (int ti = 0; ti < 4; ++ti) {
        #pragma unroll
        for (int st = 0; st < 4; ++st) {
            const int off = ti * 1024 + st * 256;
            floatx4 acc = {b2v.x, b2v.y, b2v.z, b2v.w};
            acc = __builtin_amdgcn_mfma_f32_16x16x32_bf16(af0, *(const short8*)(tp0 + off), acc, 0, 0, 0);
            acc = __builtin_amdgcn_mfma_f32_16x16x32_bf16(af1, *(const short8*)(tp1 + off), acc, 0, 0, 0);
            acc = __builtin_amdgcn_mfma_f32_16x16x32_bf16(af2, *(const short8*)(tp2 + off), acc, 0, 0, 0);
            #pragma unroll
            for (int rr = 0; rr < 4; ++rr) psum[rr] += fmaxf(acc[rr], 0.f);
        }
    }

    // ---- pool reduce across the 16 col-lanes of each group ----
    #pragma unroll
    for (int rr = 0; rr < 4; ++rr) {
        float v = psum[rr];
        v += __shfl_xor(v, 1, 64);
        v += __shfl_xor(v, 2, 64);
        v += __shfl_xor(v, 4, 64);
        v += __shfl_xor(v, 8, 64);
        if (crow == 0) pool_lds[(4 * g + rr) * DD + wave] = v * (1.f / 256.f);
    }
    __syncthreads();

    // ---- final GEMV ----
    if (tid < DD) {
        const float* pwr = pw + ((size_t)f * DD + tid) * (HID * DD);
        float o = pb[f * DD + tid];
        #pragma unroll
        for (int i = 0; i < HID * DD; ++i) o = fmaf(pwr[i], pool_lds[i], o);
        out[((size_t)b * NF + f) * DD + tid] = o;
    }
}

extern "C" void kernel_launch(void* const* d_in, const int* in_sizes, int n_in,
                              void* d_out, int out_size, void* d_ws, size_t ws_size,
                              hipStream_t stream) {
    const float* x  = (const float*)d_in[0];
    // d_in[1] = lengths (unused by reference)
    const float* w1 = (const float*)d_in[2];
    const float* b1 = (const float*)d_in[3];
    const float* w2 = (const float*)d_in[4];
    const float* b2 = (const float*)d_in[5];
    const float* pw = (const float*)d_in[6];
    const float* pb = (const float*)d_in[7];
    float* out = (float*)d_out;

    ushort* xhi   = (ushort*)d_ws;
    ushort* wpack = xhi + WPO;

    prep_k<<<dim3(5, NB), dim3(256), 0, stream>>>(x, w1, w2, xhi, wpack);
    fused_kernel<<<dim3(NF * NB), dim3(256), 0, stream>>>(xhi, wpack, b1, b2, pw, pb, out);
}